// Round 7
// baseline (463.215 us; speedup 1.0000x reference)
//
#include <hip/hip_runtime.h>
#include <hip/hip_cooperative_groups.h>
#include <cmath>

namespace cg = cooperative_groups;

#define DI __device__ __forceinline__

constexpr int BS = 32;
constexpr int NS = 65536;
constexpr int NF = 128;
constexpr int S  = 4;               // samples per thread
constexpr int TB = 256;             // threads per block
constexpr int SAMP = TB * S;        // 1024 samples per chunk
constexpr int NC = NS / SAMP;       // 64 chunks per batch
constexpr size_t U = (size_t)BS * NS;
constexpr double PI_D = 3.14159265358979323846;
constexpr float STAB = 0.999f;

// native clang vector type: __builtin_nontemporal_store requires this
typedef float f4 __attribute__((ext_vector_type(4)));
DI f4 mkf4(float a, float b, float c, float d) { f4 r; r.x=a; r.y=b; r.z=c; r.w=d; return r; }
DI void ntst4(const f4 v, float* p) { __builtin_nontemporal_store(v, (f4*)p); }

// Affine map on IIR state s=(y[t-1],y[t-2]):  s' = M*s + v.
struct M6 { float a, b, c, d, u, v; };

DI M6 comp(const M6& R, const M6& L) {   // apply L first, then R
    M6 o;
    o.a = fmaf(R.a, L.a, R.b * L.c);
    o.b = fmaf(R.a, L.b, R.b * L.d);
    o.c = fmaf(R.c, L.a, R.d * L.c);
    o.d = fmaf(R.c, L.b, R.d * L.d);
    o.u = fmaf(R.a, L.u, fmaf(R.b, L.v, R.u));
    o.v = fmaf(R.c, L.u, fmaf(R.d, L.v, R.v));
    return o;
}

DI void stepL(M6& A, float a1, float a2, float x) {
    float na = fmaf(-a1, A.a, -a2 * A.c);
    float nb = fmaf(-a1, A.b, -a2 * A.d);
    float nu = fmaf(-a1, A.u, fmaf(-a2, A.v, x));
    A.c = A.a; A.d = A.b; A.v = A.u;
    A.a = na;  A.b = nb;  A.u = nu;
}

// ---- DPP-based wave64 inclusive scan (VALU-speed) ----
template<int CTRL> DI float dppf(float x) {
    return __int_as_float(__builtin_amdgcn_update_dpp(
        __float_as_int(x), __float_as_int(x), CTRL, 0xF, 0xF, false));
}
template<int CTRL> DI M6 dpp6(const M6& s) {
    M6 o;
    o.a = dppf<CTRL>(s.a); o.b = dppf<CTRL>(s.b);
    o.c = dppf<CTRL>(s.c); o.d = dppf<CTRL>(s.d);
    o.u = dppf<CTRL>(s.u); o.v = dppf<CTRL>(s.v);
    return o;
}
DI void sel6(M6& s, const M6& t, bool p) {
    s.a = p ? t.a : s.a; s.b = p ? t.b : s.b; s.c = p ? t.c : s.c;
    s.d = p ? t.d : s.d; s.u = p ? t.u : s.u; s.v = p ? t.v : s.v;
}
DI void wave_scan6(M6& s, int lane) {    // inclusive, time order = lane order
    const int sub = lane & 15;
    { M6 o = dpp6<0x111>(s); M6 t = comp(s, o); sel6(s, t, sub >= 1); }
    { M6 o = dpp6<0x112>(s); M6 t = comp(s, o); sel6(s, t, sub >= 2); }
    { M6 o = dpp6<0x114>(s); M6 t = comp(s, o); sel6(s, t, sub >= 4); }
    { M6 o = dpp6<0x118>(s); M6 t = comp(s, o); sel6(s, t, sub >= 8); }
    { M6 o = dpp6<0x142>(s); M6 t = comp(s, o); sel6(s, t, (lane & 16) != 0); }
    { M6 o = dpp6<0x143>(s); M6 t = comp(s, o); sel6(s, t, lane >= 32); }
}

DI M6 ld6(const float* p) { M6 m; m.a=p[0]; m.b=p[1]; m.c=p[2]; m.d=p[3]; m.u=p[4]; m.v=p[5]; return m; }
DI void st6(float* p, const M6& m) { p[0]=m.a; p[1]=m.b; p[2]=m.c; p[3]=m.d; p[4]=m.u; p[5]=m.v; }

// align_corners interp position — exact integer form (t*127 < 2^23, exact)
DI void ipos(int t, int& i0, int& i1, float& fr) {
    int pn = t * 127;
    int p0 = pn / 65535;
    i0 = p0;
    i1 = (p0 + 1 > 127) ? 127 : p0 + 1;
    fr = (float)(pn - p0 * 65535) * (1.0f / 65535.0f);
}

DI float fast_tanh(float x) {            // exact at saturation (inf-safe)
    float e = __expf(2.0f * x);
    return 1.0f - 2.0f / (e + 1.0f);
}

DI void stage_frames(const float* __restrict__ logits, int b, int F, int tid,
                     float (*sfa)[2], float (*sfb)[3]) {
    if (tid < 4) {
        int fidx = F + tid; if (fidx > 127) fidx = 127;
        const float* L = logits + (size_t)(b * NF + fidx) * 5;
        float a1 = 2.0f * tanhf(L[0]) * STAB;
        float aa = fabsf(a1);
        float a2 = ((2.0f - aa) * tanhf(L[1]) * STAB + aa) * 0.5f;
        sfa[tid][0] = a1; sfa[tid][1] = a2;
        sfb[tid][0] = L[2]; sfb[tid][1] = L[3]; sfb[tid][2] = L[4];
    }
}

DI void interp4(int t0, int F, const float (*sfa)[2], const float (*sfb)[3],
                float* a1v, float* a2v, float* b0v, float* b1v, float* b2v) {
    #pragma unroll
    for (int k = 0; k < S; k++) {
        int i0, i1; float fr;
        ipos(t0 + k, i0, i1, fr);
        float w0 = 1.0f - fr;
        int l0 = i0 - F, l1 = i1 - F;
        a1v[k] = sfa[l0][0] * w0 + sfa[l1][0] * fr;
        a2v[k] = sfa[l0][1] * w0 + sfa[l1][1] * fr;
        b0v[k] = sfb[l0][0] * w0 + sfb[l1][0] * fr;
        b1v[k] = sfb[l0][1] * w0 + sfb[l1][1] * fr;
        b2v[k] = sfb[l0][2] * w0 + sfb[l1][2] * fr;
    }
}

DI void osc4(int t0, float f0, float ph, float sh, float gn, float dur, float al,
             float* x, float* env4) {
    const double inc = (double)f0 / 48000.0;
    const float partials = 12000.0f / (f0 * __log10f(f0));
    const double cum0 = (double)(t0 + 1) * inc;
    const double uu0 = cum0 - 2.0 * floor(cum0 * 0.5);            // mod 2
    const float theta0 = (float)(PI_D * uu0 + 0.5 * (double)ph);  // arg/2
    const float dth = (float)(PI_D * inc);
    #pragma unroll
    for (int k = 0; k < S; k++) {
        int t = t0 + k;
        float theta = theta0 + (float)k * dth;
        float sn, cs;
        __sincosf(theta, &sn, &cs);
        float sq = fast_tanh(1.57079632679f * partials * (2.0f * sn * cs));
        float dry0 = (1.0f - 0.5f * sh) * sq * (1.0f + sh * cs);
        float tsec = (float)t * (1.0f / 48000.0f);
        float env = 0.0f;
        if (tsec <= dur) {
            float ramp = 1.0f - tsec / dur;
            ramp = ramp < 0.001f ? 0.001f : (ramp > 1.0f ? 1.0f : ramp);
            env = __expf(al * __logf(ramp));
        }
        env4[k] = env;
        x[k] = dry0 * gn * env;
    }
}

// --------- fused cooperative kernel: phase1 (K1 body) | grid.sync | phase2 ---
__global__ __launch_bounds__(TB, 8) void k_all(
    const float* __restrict__ f0_hz, const float* __restrict__ note_dur,
    const float* __restrict__ phase, const float* __restrict__ logits,
    const float* __restrict__ osc_shape, const float* __restrict__ osc_gain,
    const float* __restrict__ dist_gain, const float* __restrict__ alpha,
    float* __restrict__ ws_chunk, float* __restrict__ out) {
    __shared__ float sfa[4][2], sfb[4][3], wt[4][6], sv[NC][2];
    __shared__ float sstage[SAMP * 3];   // 12 KB repack buffer (a3, then bc)
    const int bid = blockIdx.x;
    const int b = bid / NC, c = bid % NC;
    const int tid = threadIdx.x;
    const int t0 = c * SAMP + tid * S;
    const size_t g0 = (size_t)b * NS + t0;
    const int F = (c * SAMP * 127) / 65535;

    // ================= phase 1: osc + env + coeff planes + chunk summary =====
    stage_frames(logits, b, F, tid, sfa, sfb);

    float x[S], env4[S];
    osc4(t0, f0_hz[b], phase[b], osc_shape[b], osc_gain[b], note_dur[b], alpha[b],
         x, env4);
    __syncthreads();   // frame staging visible

    float a1v[S], a2v[S], b0v[S], b1v[S], b2v[S];
    interp4(t0, F, sfa, sfb, a1v, a2v, b0v, b1v, b2v);

    ntst4(mkf4(x[0], x[1], x[2], x[3]), &out[g0]);                       // dry
    ntst4(mkf4(env4[0], env4[1], env4[2], env4[3]), &out[2 * U + g0]);   // env

    // a3 plane via LDS repack (thread's 12 floats ARE linear order)
    const int tw = tid * 12;
    const size_t blk0 = ((size_t)b * NS + (size_t)c * SAMP) * 3;
    *(f4*)&sstage[tw + 0] = mkf4(1.0f, a1v[0], a2v[0], 1.0f);
    *(f4*)&sstage[tw + 4] = mkf4(a1v[1], a2v[1], 1.0f, a1v[2]);
    *(f4*)&sstage[tw + 8] = mkf4(a2v[2], 1.0f, a1v[3], a2v[3]);
    __syncthreads();
    {
        float* dst = out + 4 * U + blk0;
        #pragma unroll
        for (int r = 0; r < 3; r++) {
            int wi = r * (TB * 4) + tid * 4;
            ntst4(*(const f4*)&sstage[wi], &dst[wi]);
        }
    }
    __syncthreads();
    *(f4*)&sstage[tw + 0] = mkf4(b0v[0], b1v[0], b2v[0], b0v[1]);
    *(f4*)&sstage[tw + 4] = mkf4(b1v[1], b2v[1], b0v[2], b1v[2]);
    *(f4*)&sstage[tw + 8] = mkf4(b2v[2], b0v[3], b1v[3], b2v[3]);
    __syncthreads();
    {
        float* dst = out + 7 * U + blk0;
        #pragma unroll
        for (int r = 0; r < 3; r++) {
            int wi = r * (TB * 4) + tid * 4;
            ntst4(*(const f4*)&sstage[wi], &dst[wi]);
        }
    }

    // chunk summary: serial 4-step aggregate, then block scan
    M6 A; A.a = -a1v[0]; A.b = -a2v[0]; A.c = 1.0f; A.d = 0.0f; A.u = x[0]; A.v = 0.0f;
    #pragma unroll
    for (int k = 1; k < S; k++) stepL(A, a1v[k], a2v[k], x[k]);

    const int lane = tid & 63, w = tid >> 6;
    wave_scan6(A, lane);
    if (lane == 63) st6(wt[w], A);
    __syncthreads();
    if (tid == TB - 1) {
        M6 p = ld6(wt[0]);
        p = comp(ld6(wt[1]), p);
        p = comp(ld6(wt[2]), p);
        M6 tot = comp(A, p);
        // publish: 5 relaxed + final RELEASE (forces L2 writeback to the
        // coherent point BEFORE the release store becomes visible — the part
        // R6 was missing; exactly R2's proven pairing, spin replaced by sync)
        float* wp = ws_chunk + (size_t)(b * NC + c) * 6;
        __hip_atomic_store(wp + 0, tot.a, __ATOMIC_RELAXED, __HIP_MEMORY_SCOPE_AGENT);
        __hip_atomic_store(wp + 1, tot.b, __ATOMIC_RELAXED, __HIP_MEMORY_SCOPE_AGENT);
        __hip_atomic_store(wp + 2, tot.c, __ATOMIC_RELAXED, __HIP_MEMORY_SCOPE_AGENT);
        __hip_atomic_store(wp + 3, tot.d, __ATOMIC_RELAXED, __HIP_MEMORY_SCOPE_AGENT);
        __hip_atomic_store(wp + 4, tot.u, __ATOMIC_RELAXED, __HIP_MEMORY_SCOPE_AGENT);
        __hip_atomic_store(wp + 5, tot.v, __ATOMIC_RELEASE, __HIP_MEMORY_SCOPE_AGENT);
    }

    // ================= grid-wide barrier =====================================
    cg::this_grid().sync();

    // ================= phase 2: cross-chunk prefix + apply + FIR + tanh ======
    // x[], A, wt/sfa/sfb (LDS) persist — K2's whole front half is gone.
    if (tid < NC) {
        const float* wp = ws_chunk + (size_t)(b * NC + tid) * 6;
        M6 cs;
        // acquire FIRST on the release-published field (invalidates stale L2),
        // then relaxed loads of the rest are ordered after it.
        cs.v = __hip_atomic_load(wp + 5, __ATOMIC_ACQUIRE, __HIP_MEMORY_SCOPE_AGENT);
        cs.a = __hip_atomic_load(wp + 0, __ATOMIC_RELAXED, __HIP_MEMORY_SCOPE_AGENT);
        cs.b = __hip_atomic_load(wp + 1, __ATOMIC_RELAXED, __HIP_MEMORY_SCOPE_AGENT);
        cs.c = __hip_atomic_load(wp + 2, __ATOMIC_RELAXED, __HIP_MEMORY_SCOPE_AGENT);
        cs.d = __hip_atomic_load(wp + 3, __ATOMIC_RELAXED, __HIP_MEMORY_SCOPE_AGENT);
        cs.u = __hip_atomic_load(wp + 4, __ATOMIC_RELAXED, __HIP_MEMORY_SCOPE_AGENT);
        wave_scan6(cs, tid);
        sv[tid][0] = cs.u; sv[tid][1] = cs.v;   // state after chunk tid (zero init)
    }
    __syncthreads();
    const float s0 = c ? sv[c - 1][0] : 0.0f;   // y[-1] entering this chunk
    const float s1 = c ? sv[c - 1][1] : 0.0f;   // y[-2]

    // block-exclusive prefix E from persisted wt + wave-scanned A
    M6 P; P.a = 1.f; P.b = 0.f; P.c = 0.f; P.d = 1.f; P.u = 0.f; P.v = 0.f;
    for (int i = 0; i < w; i++) P = comp(ld6(wt[i]), P);
    M6 prev;
    prev.a = __shfl_up(A.a, 1, 64); prev.b = __shfl_up(A.b, 1, 64);
    prev.c = __shfl_up(A.c, 1, 64); prev.d = __shfl_up(A.d, 1, 64);
    prev.u = __shfl_up(A.u, 1, 64); prev.v = __shfl_up(A.v, 1, 64);
    M6 E = (lane == 0) ? P : comp(prev, P);

    float y1 = fmaf(E.a, s0, fmaf(E.b, s1, E.u));
    float y2 = fmaf(E.c, s0, fmaf(E.d, s1, E.v));
    const float ys0 = y1, ys1 = y2;

    float y[S];
    #pragma unroll
    for (int k = 0; k < S; k++) {
        y[k] = fmaf(-a1v[k], y1, fmaf(-a2v[k], y2, x[k]));
        y2 = y1; y1 = y[k];
    }

    const float dg = dist_gain[b];
    float yab[S], wet[S];
    #pragma unroll
    for (int k = 0; k < S; k++) {
        float ym1 = (k >= 1) ? y[k - 1] : ys0;
        float ym2 = (k >= 2) ? y[k - 2] : ((k == 1) ? ys0 : ys1);
        yab[k] = b0v[k] * y[k] + b1v[k] * ym1 + b2v[k] * ym2;
        wet[k] = fast_tanh(yab[k] * dg);
    }

    ntst4(mkf4(wet[0], wet[1], wet[2], wet[3]), &out[U + g0]);
    ntst4(mkf4(yab[0], yab[1], yab[2], yab[3]), &out[3 * U + g0]);
    ntst4(mkf4(y[0], y[1], y[2], y[3]), &out[10 * U + g0]);
}

// ---------------- fallback two-kernel path (proven, R5) -----------------------
__global__ __launch_bounds__(TB) void k_osc(
    const float* __restrict__ f0_hz, const float* __restrict__ note_dur,
    const float* __restrict__ phase, const float* __restrict__ logits,
    const float* __restrict__ osc_shape, const float* __restrict__ osc_gain,
    const float* __restrict__ alpha,
    float* __restrict__ ws_chunk, float* __restrict__ out) {
    __shared__ float sfa[4][2], sfb[4][3], wt[4][6];
    __shared__ float sstage[SAMP * 3];
    const int bid = blockIdx.x;
    const int b = bid / NC, c = bid % NC;
    const int tid = threadIdx.x;
    const int t0 = c * SAMP + tid * S;
    const size_t g0 = (size_t)b * NS + t0;
    const int F = (c * SAMP * 127) / 65535;

    stage_frames(logits, b, F, tid, sfa, sfb);
    float x[S], env4[S];
    osc4(t0, f0_hz[b], phase[b], osc_shape[b], osc_gain[b], note_dur[b], alpha[b],
         x, env4);
    __syncthreads();

    float a1v[S], a2v[S], b0v[S], b1v[S], b2v[S];
    interp4(t0, F, sfa, sfb, a1v, a2v, b0v, b1v, b2v);

    ntst4(mkf4(x[0], x[1], x[2], x[3]), &out[g0]);
    ntst4(mkf4(env4[0], env4[1], env4[2], env4[3]), &out[2 * U + g0]);

    const int tw = tid * 12;
    const size_t blk0 = ((size_t)b * NS + (size_t)c * SAMP) * 3;
    *(f4*)&sstage[tw + 0] = mkf4(1.0f, a1v[0], a2v[0], 1.0f);
    *(f4*)&sstage[tw + 4] = mkf4(a1v[1], a2v[1], 1.0f, a1v[2]);
    *(f4*)&sstage[tw + 8] = mkf4(a2v[2], 1.0f, a1v[3], a2v[3]);
    __syncthreads();
    {
        float* dst = out + 4 * U + blk0;
        #pragma unroll
        for (int r = 0; r < 3; r++) {
            int wi = r * (TB * 4) + tid * 4;
            ntst4(*(const f4*)&sstage[wi], &dst[wi]);
        }
    }
    __syncthreads();
    *(f4*)&sstage[tw + 0] = mkf4(b0v[0], b1v[0], b2v[0], b0v[1]);
    *(f4*)&sstage[tw + 4] = mkf4(b1v[1], b2v[1], b0v[2], b1v[2]);
    *(f4*)&sstage[tw + 8] = mkf4(b2v[2], b0v[3], b1v[3], b2v[3]);
    __syncthreads();
    {
        float* dst = out + 7 * U + blk0;
        #pragma unroll
        for (int r = 0; r < 3; r++) {
            int wi = r * (TB * 4) + tid * 4;
            ntst4(*(const f4*)&sstage[wi], &dst[wi]);
        }
    }

    M6 A; A.a = -a1v[0]; A.b = -a2v[0]; A.c = 1.0f; A.d = 0.0f; A.u = x[0]; A.v = 0.0f;
    #pragma unroll
    for (int k = 1; k < S; k++) stepL(A, a1v[k], a2v[k], x[k]);

    const int lane = tid & 63, w = tid >> 6;
    wave_scan6(A, lane);
    if (lane == 63) st6(wt[w], A);
    __syncthreads();
    if (tid == TB - 1) {
        M6 p = ld6(wt[0]);
        p = comp(ld6(wt[1]), p);
        p = comp(ld6(wt[2]), p);
        M6 tot = comp(A, p);
        st6(ws_chunk + ((size_t)b * NC + c) * 6, tot);
    }
}

__global__ __launch_bounds__(TB) void k_iir(
    const float* __restrict__ f0_hz, const float* __restrict__ note_dur,
    const float* __restrict__ phase, const float* __restrict__ logits,
    const float* __restrict__ osc_shape, const float* __restrict__ osc_gain,
    const float* __restrict__ dist_gain, const float* __restrict__ alpha,
    const float* __restrict__ ws_chunk, float* __restrict__ out) {
    __shared__ float sfa[4][2], sfb[4][3], wt[4][6], sv[NC][2];
    const int bid = blockIdx.x;
    const int b = bid / NC, c = bid % NC;
    const int tid = threadIdx.x;
    const int t0 = c * SAMP + tid * S;
    const size_t g0 = (size_t)b * NS + t0;
    const int F = (c * SAMP * 127) / 65535;

    stage_frames(logits, b, F, tid, sfa, sfb);

    if (tid < NC) {
        M6 cs = ld6(ws_chunk + ((size_t)b * NC + tid) * 6);
        wave_scan6(cs, tid);
        sv[tid][0] = cs.u; sv[tid][1] = cs.v;
    }

    float x[S], env4[S];
    osc4(t0, f0_hz[b], phase[b], osc_shape[b], osc_gain[b], note_dur[b], alpha[b],
         x, env4);

    __syncthreads();
    const float s0 = c ? sv[c - 1][0] : 0.0f;
    const float s1 = c ? sv[c - 1][1] : 0.0f;

    float a1v[S], a2v[S], b0v[S], b1v[S], b2v[S];
    interp4(t0, F, sfa, sfb, a1v, a2v, b0v, b1v, b2v);

    M6 A; A.a = -a1v[0]; A.b = -a2v[0]; A.c = 1.0f; A.d = 0.0f; A.u = x[0]; A.v = 0.0f;
    #pragma unroll
    for (int k = 1; k < S; k++) stepL(A, a1v[k], a2v[k], x[k]);

    const int lane = tid & 63, w = tid >> 6;
    wave_scan6(A, lane);
    if (lane == 63) st6(wt[w], A);
    __syncthreads();

    M6 P; P.a = 1.f; P.b = 0.f; P.c = 0.f; P.d = 1.f; P.u = 0.f; P.v = 0.f;
    for (int i = 0; i < w; i++) P = comp(ld6(wt[i]), P);
    M6 prev;
    prev.a = __shfl_up(A.a, 1, 64); prev.b = __shfl_up(A.b, 1, 64);
    prev.c = __shfl_up(A.c, 1, 64); prev.d = __shfl_up(A.d, 1, 64);
    prev.u = __shfl_up(A.u, 1, 64); prev.v = __shfl_up(A.v, 1, 64);
    M6 E = (lane == 0) ? P : comp(prev, P);

    float y1 = fmaf(E.a, s0, fmaf(E.b, s1, E.u));
    float y2 = fmaf(E.c, s0, fmaf(E.d, s1, E.v));
    const float ys0 = y1, ys1 = y2;

    float y[S];
    #pragma unroll
    for (int k = 0; k < S; k++) {
        y[k] = fmaf(-a1v[k], y1, fmaf(-a2v[k], y2, x[k]));
        y2 = y1; y1 = y[k];
    }

    const float dg = dist_gain[b];
    float yab[S], wet[S];
    #pragma unroll
    for (int k = 0; k < S; k++) {
        float ym1 = (k >= 1) ? y[k - 1] : ys0;
        float ym2 = (k >= 2) ? y[k - 2] : ((k == 1) ? ys0 : ys1);
        yab[k] = b0v[k] * y[k] + b1v[k] * ym1 + b2v[k] * ym2;
        wet[k] = fast_tanh(yab[k] * dg);
    }

    ntst4(mkf4(wet[0], wet[1], wet[2], wet[3]), &out[U + g0]);
    ntst4(mkf4(yab[0], yab[1], yab[2], yab[3]), &out[3 * U + g0]);
    ntst4(mkf4(y[0], y[1], y[2], y[3]), &out[10 * U + g0]);
}

extern "C" void kernel_launch(void* const* d_in, const int* in_sizes, int n_in,
                              void* d_out, int out_size, void* d_ws, size_t ws_size,
                              hipStream_t stream) {
    const float* f0   = (const float*)d_in[0];
    const float* dur  = (const float*)d_in[1];
    const float* ph   = (const float*)d_in[2];
    const float* lg   = (const float*)d_in[3];
    const float* shp  = (const float*)d_in[4];
    const float* gn   = (const float*)d_in[5];
    const float* dist = (const float*)d_in[6];
    const float* alp  = (const float*)d_in[7];
    float* out = (float*)d_out;
    float* ws_chunk = (float*)d_ws;            // BS*NC*6 f32 = 48 KB (proven safe)

    void* args[] = {
        (void*)&f0, (void*)&dur, (void*)&ph, (void*)&lg, (void*)&shp,
        (void*)&gn, (void*)&dist, (void*)&alp, (void*)&ws_chunk, (void*)&out
    };
    hipError_t e = hipLaunchCooperativeKernel((void*)k_all, dim3(BS * NC), dim3(TB),
                                              args, 0, stream);
    if (e != hipSuccess) {   // e.g. capture-unsupported: proven two-kernel path
        k_osc<<<BS * NC, TB, 0, stream>>>(f0, dur, ph, lg, shp, gn, alp, ws_chunk, out);
        k_iir<<<BS * NC, TB, 0, stream>>>(f0, dur, ph, lg, shp, gn, dist, alp, ws_chunk, out);
    }
}

// Round 8
// 124.315 us; speedup vs baseline: 3.7261x; 3.7261x over previous
//
#include <hip/hip_runtime.h>
#include <cmath>

#define DI __device__ __forceinline__

constexpr int BS = 32;
constexpr int NS = 65536;
constexpr int NF = 128;
constexpr int S  = 4;               // samples per thread (R5 optimum)
constexpr int TB = 256;             // threads per block
constexpr int SAMP = TB * S;        // 1024 samples per chunk
constexpr int NC = NS / SAMP;       // 64 chunks per batch
constexpr size_t U = (size_t)BS * NS;
constexpr double PI_D = 3.14159265358979323846;
constexpr float STAB = 0.999f;

// Affine map on IIR state s=(y[t-1],y[t-2]):  s' = M*s + v.
// M=[[a,b],[c,d]], v=(u,v). One sample: M=[[-a1,-a2],[1,0]], v=(x,0).
struct M6 { float a, b, c, d, u, v; };

DI M6 comp(const M6& R, const M6& L) {   // apply L first, then R
    M6 o;
    o.a = fmaf(R.a, L.a, R.b * L.c);
    o.b = fmaf(R.a, L.b, R.b * L.d);
    o.c = fmaf(R.c, L.a, R.d * L.c);
    o.d = fmaf(R.c, L.b, R.d * L.d);
    o.u = fmaf(R.a, L.u, fmaf(R.b, L.v, R.u));
    o.v = fmaf(R.c, L.u, fmaf(R.d, L.v, R.v));
    return o;
}

// Prepend one companion step (a1,a2,x) on the LEFT (later in time) of A.
DI void stepL(M6& A, float a1, float a2, float x) {
    float na = fmaf(-a1, A.a, -a2 * A.c);
    float nb = fmaf(-a1, A.b, -a2 * A.d);
    float nu = fmaf(-a1, A.u, fmaf(-a2, A.v, x));
    A.c = A.a; A.d = A.b; A.v = A.u;
    A.a = na;  A.b = nb;  A.u = nu;
}

DI void wave_scan6(M6& s, int lane) {    // inclusive, time order = lane order
    #pragma unroll
    for (int d = 1; d < 64; d <<= 1) {
        M6 o;
        o.a = __shfl_up(s.a, d, 64); o.b = __shfl_up(s.b, d, 64);
        o.c = __shfl_up(s.c, d, 64); o.d = __shfl_up(s.d, d, 64);
        o.u = __shfl_up(s.u, d, 64); o.v = __shfl_up(s.v, d, 64);
        M6 t = comp(s, o);
        bool p = lane >= d;
        s.a = p ? t.a : s.a; s.b = p ? t.b : s.b; s.c = p ? t.c : s.c;
        s.d = p ? t.d : s.d; s.u = p ? t.u : s.u; s.v = p ? t.v : s.v;
    }
}

DI M6 ld6(const float* p) { M6 m; m.a=p[0]; m.b=p[1]; m.c=p[2]; m.d=p[3]; m.u=p[4]; m.v=p[5]; return m; }
DI void st6(float* p, const M6& m) { p[0]=m.a; p[1]=m.b; p[2]=m.c; p[3]=m.d; p[4]=m.u; p[5]=m.v; }

// align_corners interp position — exact integer form (t*127 < 2^23, exact)
DI void ipos(int t, int& i0, int& i1, float& fr) {
    int pn = t * 127;
    int p0 = pn / 65535;                 // magic-mul div by constant
    i0 = p0;
    i1 = (p0 + 1 > 127) ? 127 : p0 + 1;
    fr = (float)(pn - p0 * 65535) * (1.0f / 65535.0f);
}

DI float fast_tanh(float x) {            // exact at saturation (inf-safe)
    float e = __expf(2.0f * x);
    return 1.0f - 2.0f / (e + 1.0f);
}

// Stage the <=4 frames a 1024-sample chunk touches.
DI void stage_frames(const float* __restrict__ logits, int b, int F, int tid,
                     float (*sfa)[2], float (*sfb)[3]) {
    if (tid < 4) {
        int fidx = F + tid; if (fidx > 127) fidx = 127;
        const float* L = logits + (size_t)(b * NF + fidx) * 5;
        float a1 = 2.0f * tanhf(L[0]) * STAB;
        float aa = fabsf(a1);
        float a2 = ((2.0f - aa) * tanhf(L[1]) * STAB + aa) * 0.5f;
        sfa[tid][0] = a1; sfa[tid][1] = a2;
        sfb[tid][0] = L[2]; sfb[tid][1] = L[3]; sfb[tid][2] = L[4];
    }
}

// Per-sample interp from staged frames (l-indices relative to F).
DI void interp4(int t0, int F, const float (*sfa)[2], const float (*sfb)[3],
                float* a1v, float* a2v, float* b0v, float* b1v, float* b2v) {
    #pragma unroll
    for (int k = 0; k < S; k++) {
        int i0, i1; float fr;
        ipos(t0 + k, i0, i1, fr);
        float w0 = 1.0f - fr;
        int l0 = i0 - F, l1 = i1 - F;
        a1v[k] = sfa[l0][0] * w0 + sfa[l1][0] * fr;
        a2v[k] = sfa[l0][1] * w0 + sfa[l1][1] * fr;
        b0v[k] = sfb[l0][0] * w0 + sfb[l1][0] * fr;
        b1v[k] = sfb[l0][1] * w0 + sfb[l1][1] * fr;
        b2v[k] = sfb[l0][2] * w0 + sfb[l1][2] * fr;
    }
}

// ---------------- K1: osc + env + coeff planes + chunk summary ----------------
__global__ __launch_bounds__(TB) void k_osc(
    const float* __restrict__ f0_hz, const float* __restrict__ note_dur,
    const float* __restrict__ phase, const float* __restrict__ logits,
    const float* __restrict__ osc_shape, const float* __restrict__ osc_gain,
    const float* __restrict__ alpha,
    float* __restrict__ ws_chunk, float* __restrict__ out) {
    __shared__ float sfa[4][2], sfb[4][3], wt[4][6];
    __shared__ float sstage[SAMP * 3];   // 12 KB repack buffer (a3, then bc)
    const int bid = blockIdx.x;
    const int b = bid / NC, c = bid % NC;
    const int tid = threadIdx.x;
    const int t0 = c * SAMP + tid * S;
    const size_t g0 = (size_t)b * NS + t0;
    const int F = (c * SAMP * 127) / 65535;

    stage_frames(logits, b, F, tid, sfa, sfb);

    const float f0 = f0_hz[b];
    const float ph = phase[b];
    const float sh = osc_shape[b];
    const float gn = osc_gain[b];
    const float dur = note_dur[b];
    const float al = alpha[b];
    const double inc = (double)f0 / 48000.0;
    const float partials = 12000.0f / (f0 * __log10f(f0));

    // one f64 phase reduction per thread; f32 increments within (k<4)
    const double cum0 = (double)(t0 + 1) * inc;
    const double uu0 = cum0 - 2.0 * floor(cum0 * 0.5);            // mod 2
    const float theta0 = (float)(PI_D * uu0 + 0.5 * (double)ph);  // arg/2
    const float dth = (float)(PI_D * inc);

    float x[S], env4[S];
    #pragma unroll
    for (int k = 0; k < S; k++) {
        int t = t0 + k;
        float theta = theta0 + (float)k * dth;
        float sn, cs;
        __sincosf(theta, &sn, &cs);
        float sq = fast_tanh(1.57079632679f * partials * (2.0f * sn * cs));
        float dry0 = (1.0f - 0.5f * sh) * sq * (1.0f + sh * cs);
        float tsec = (float)t * (1.0f / 48000.0f);
        float env = 0.0f;
        if (tsec <= dur) {
            float ramp = 1.0f - tsec / dur;
            ramp = ramp < 0.001f ? 0.001f : (ramp > 1.0f ? 1.0f : ramp);
            env = __expf(al * __logf(ramp));
        }
        env4[k] = env;
        x[k] = dry0 * gn * env;
    }
    __syncthreads();   // frame staging visible

    float a1v[S], a2v[S], b0v[S], b1v[S], b2v[S];
    interp4(t0, F, sfa, sfb, a1v, a2v, b0v, b1v, b2v);

    // --- coalesced plane stores (dry/env already lane-contiguous)
    *(float4*)&out[g0]         = make_float4(x[0], x[1], x[2], x[3]);             // dry
    *(float4*)&out[2 * U + g0] = make_float4(env4[0], env4[1], env4[2], env4[3]); // env

    // --- a3 plane via LDS repack: thread's 12 floats ARE linear order [12*tid, +12)
    const int tw = tid * 12;
    const size_t blk0 = ((size_t)b * NS + (size_t)c * SAMP) * 3;  // block's 3072-float region
    *(float4*)&sstage[tw + 0] = make_float4(1.0f, a1v[0], a2v[0], 1.0f);
    *(float4*)&sstage[tw + 4] = make_float4(a1v[1], a2v[1], 1.0f, a1v[2]);
    *(float4*)&sstage[tw + 8] = make_float4(a2v[2], 1.0f, a1v[3], a2v[3]);
    __syncthreads();
    {
        float* dst = out + 4 * U + blk0;
        #pragma unroll
        for (int r = 0; r < 3; r++) {
            int wi = r * (TB * 4) + tid * 4;                      // contiguous per wave
            *(float4*)&dst[wi] = *(const float4*)&sstage[wi];
        }
    }
    __syncthreads();
    // --- bc plane, reuse buffer
    *(float4*)&sstage[tw + 0] = make_float4(b0v[0], b1v[0], b2v[0], b0v[1]);
    *(float4*)&sstage[tw + 4] = make_float4(b1v[1], b2v[1], b0v[2], b1v[2]);
    *(float4*)&sstage[tw + 8] = make_float4(b2v[2], b0v[3], b1v[3], b2v[3]);
    __syncthreads();
    {
        float* dst = out + 7 * U + blk0;
        #pragma unroll
        for (int r = 0; r < 3; r++) {
            int wi = r * (TB * 4) + tid * 4;
            *(float4*)&dst[wi] = *(const float4*)&sstage[wi];
        }
    }

    // --- chunk summary: serial 4-step aggregate, then block scan
    M6 A; A.a = -a1v[0]; A.b = -a2v[0]; A.c = 1.0f; A.d = 0.0f; A.u = x[0]; A.v = 0.0f;
    #pragma unroll
    for (int k = 1; k < S; k++) stepL(A, a1v[k], a2v[k], x[k]);

    const int lane = tid & 63, w = tid >> 6;
    wave_scan6(A, lane);
    if (lane == 63) st6(wt[w], A);
    __syncthreads();
    if (tid == TB - 1) {
        M6 p = ld6(wt[0]);
        p = comp(ld6(wt[1]), p);
        p = comp(ld6(wt[2]), p);
        M6 tot = comp(A, p);
        st6(ws_chunk + ((size_t)b * NC + c) * 6, tot);
    }
}

// ---------------- K2: cross-chunk prefix + in-chunk scan + FIR + tanh ---------
__global__ __launch_bounds__(TB) void k_iir(
    const float* __restrict__ logits, const float* __restrict__ dist_gain,
    const float* __restrict__ ws_chunk, float* __restrict__ out) {
    __shared__ float sfa[4][2], sfb[4][3], wt[4][6], sv[NC][2];
    const int bid = blockIdx.x;
    const int b = bid / NC, c = bid % NC;
    const int tid = threadIdx.x;
    const int t0 = c * SAMP + tid * S;
    const size_t g0 = (size_t)b * NS + t0;
    const int F = (c * SAMP * 127) / 65535;

    stage_frames(logits, b, F, tid, sfa, sfb);

    // phase A: wave 0 scans this batch's 64 chunk summaries
    if (tid < NC) {
        M6 cs = ld6(ws_chunk + ((size_t)b * NC + tid) * 6);
        wave_scan6(cs, tid);
        sv[tid][0] = cs.u; sv[tid][1] = cs.v;   // state after chunk tid (zero init)
    }

    float4 xv = *(const float4*)&out[g0];       // dry (plane 0)
    float x[S] = {xv.x, xv.y, xv.z, xv.w};

    __syncthreads();
    const float s0 = c ? sv[c - 1][0] : 0.0f;   // y[-1] entering this chunk
    const float s1 = c ? sv[c - 1][1] : 0.0f;   // y[-2]

    float a1v[S], a2v[S], b0v[S], b1v[S], b2v[S];
    interp4(t0, F, sfa, sfb, a1v, a2v, b0v, b1v, b2v);

    // per-thread 4-step aggregate + inclusive block scan
    M6 A; A.a = -a1v[0]; A.b = -a2v[0]; A.c = 1.0f; A.d = 0.0f; A.u = x[0]; A.v = 0.0f;
    #pragma unroll
    for (int k = 1; k < S; k++) stepL(A, a1v[k], a2v[k], x[k]);

    const int lane = tid & 63, w = tid >> 6;
    wave_scan6(A, lane);
    if (lane == 63) st6(wt[w], A);
    __syncthreads();

    M6 P; P.a = 1.f; P.b = 0.f; P.c = 0.f; P.d = 1.f; P.u = 0.f; P.v = 0.f;
    for (int i = 0; i < w; i++) P = comp(ld6(wt[i]), P);
    M6 prev;
    prev.a = __shfl_up(A.a, 1, 64); prev.b = __shfl_up(A.b, 1, 64);
    prev.c = __shfl_up(A.c, 1, 64); prev.d = __shfl_up(A.d, 1, 64);
    prev.u = __shfl_up(A.u, 1, 64); prev.v = __shfl_up(A.v, 1, 64);
    M6 E = (lane == 0) ? P : comp(prev, P);     // aggregate of samples before this thread

    // state entering this thread's 4 samples
    float y1 = fmaf(E.a, s0, fmaf(E.b, s1, E.u));
    float y2 = fmaf(E.c, s0, fmaf(E.d, s1, E.v));
    const float ys0 = y1, ys1 = y2;

    float y[S];
    #pragma unroll
    for (int k = 0; k < S; k++) {
        y[k] = fmaf(-a1v[k], y1, fmaf(-a2v[k], y2, x[k]));
        y2 = y1; y1 = y[k];
    }

    const float dg = dist_gain[b];
    float yab[S], wet[S];
    #pragma unroll
    for (int k = 0; k < S; k++) {
        float ym1 = (k >= 1) ? y[k - 1] : ys0;
        float ym2 = (k >= 2) ? y[k - 2] : ((k == 1) ? ys0 : ys1);
        yab[k] = b0v[k] * y[k] + b1v[k] * ym1 + b2v[k] * ym2;
        wet[k] = fast_tanh(yab[k] * dg);
    }

    *(float4*)&out[U + g0]      = make_float4(wet[0], wet[1], wet[2], wet[3]);
    *(float4*)&out[3 * U + g0]  = make_float4(yab[0], yab[1], yab[2], yab[3]);
    *(float4*)&out[10 * U + g0] = make_float4(y[0], y[1], y[2], y[3]);
}

extern "C" void kernel_launch(void* const* d_in, const int* in_sizes, int n_in,
                              void* d_out, int out_size, void* d_ws, size_t ws_size,
                              hipStream_t stream) {
    const float* f0   = (const float*)d_in[0];
    const float* dur  = (const float*)d_in[1];
    const float* ph   = (const float*)d_in[2];
    const float* lg   = (const float*)d_in[3];
    const float* shp  = (const float*)d_in[4];
    const float* gn   = (const float*)d_in[5];
    const float* dist = (const float*)d_in[6];
    const float* alp  = (const float*)d_in[7];
    float* out = (float*)d_out;
    float* ws_chunk = (float*)d_ws;            // BS*NC*6 f32 = 48 KB (proven safe)

    k_osc<<<BS * NC, TB, 0, stream>>>(f0, dur, ph, lg, shp, gn, alp, ws_chunk, out);
    k_iir<<<BS * NC, TB, 0, stream>>>(lg, dist, ws_chunk, out);
}